// Round 1
// baseline (590.504 us; speedup 1.0000x reference)
//
#include <hip/hip_runtime.h>
#include <hip/hip_bf16.h>
#include <stdint.h>

typedef __bf16 bf16_t;
typedef __bf16 bf16x8 __attribute__((ext_vector_type(8)));
typedef float  f32x4  __attribute__((ext_vector_type(4)));

#define B_    4
#define T_    2048
#define C_    1024
#define NH    16
#define HD    64
#define M_TOT (B_ * T_)   // 8192

// ---------------- convert x (fp32) -> bf16, flat ----------------
__global__ void conv_x_kernel(const float* __restrict__ x, bf16_t* __restrict__ xb, int n4) {
    int i = blockIdx.x * blockDim.x + threadIdx.x;
    int stride = gridDim.x * blockDim.x;
    for (; i < n4; i += stride) {
        float4 v = reinterpret_cast<const float4*>(x)[i];
        union { bf16_t h[4]; uint2 u; } p;
        p.h[0] = (bf16_t)v.x; p.h[1] = (bf16_t)v.y;
        p.h[2] = (bf16_t)v.z; p.h[3] = (bf16_t)v.w;
        reinterpret_cast<uint2*>(xb)[i] = p.u;
    }
}

// ---------------- transpose + convert: w[K][N] fp32 -> wt[N][K] bf16 ----------------
__global__ void transpose_w_kernel(const float* __restrict__ w, bf16_t* __restrict__ wt,
                                   int K, int N) {
    __shared__ float tile[32][33];
    int n0 = blockIdx.x * 32, k0 = blockIdx.y * 32;
    int tx = threadIdx.x, ty = threadIdx.y;
    #pragma unroll
    for (int i = 0; i < 32; i += 8)
        tile[ty + i][tx] = w[(size_t)(k0 + ty + i) * N + n0 + tx];
    __syncthreads();
    #pragma unroll
    for (int i = 0; i < 32; i += 8)
        wt[(size_t)(n0 + ty + i) * K + k0 + tx] = (bf16_t)tile[tx][ty + i];
}

// ---------------- GEMM: C[M][N] = A[M][K](bf16) * Bt[N][K](bf16)^T ----------------
// MODE 0: write fp32 C to Cout
// MODE 1: QKV epilogue -> Q (scaled 1/8) [B,H,T,D], K [B,H,T,D], V transposed [B,H,D,T]
#define BM 128
#define BN 128
#define BKK 64

template<int MODE>
__global__ __launch_bounds__(256) void gemm_bt_kernel(
    const bf16_t* __restrict__ A, const bf16_t* __restrict__ Bt,
    float* __restrict__ Cout,
    bf16_t* __restrict__ Qo, bf16_t* __restrict__ Ko, bf16_t* __restrict__ Vt,
    int M, int N, int K)
{
    __shared__ __align__(16) char lds[BM * 128 + BN * 128];  // A: 16KB, B: 16KB (BK=64 bf16)
    const int tid  = threadIdx.x;
    const int lane = tid & 63;
    const int wid  = tid >> 6;
    const int wm   = wid >> 1, wn = wid & 1;
    const int mbase = blockIdx.y * BM;
    const int nbase = blockIdx.x * BN;

    f32x4 acc[4][4] = {};

    for (int k0 = 0; k0 < K; k0 += BKK) {
        __syncthreads();
        // stage A and B tiles (reg-staged, XOR-swizzled rows: stride 128B)
        #pragma unroll
        for (int c = 0; c < 4; ++c) {
            int li   = tid + c * 256;      // 0..1023 chunks of 8 bf16
            int row  = li >> 3;            // 0..127
            int col8 = li & 7;             // 0..7
            int byte = (row * 128 + col8 * 16) ^ ((row & 7) << 4);
            uint4 va = *reinterpret_cast<const uint4*>(A + (size_t)(mbase + row) * K + k0 + col8 * 8);
            *reinterpret_cast<uint4*>(lds + byte) = va;
            uint4 vb = *reinterpret_cast<const uint4*>(Bt + (size_t)(nbase + row) * K + k0 + col8 * 8);
            *reinterpret_cast<uint4*>(lds + 16384 + byte) = vb;
        }
        __syncthreads();
        #pragma unroll
        for (int kk = 0; kk < 2; ++kk) {
            bf16x8 af[4], bfr[4];
            #pragma unroll
            for (int i = 0; i < 4; ++i) {
                int rowa  = wm * 64 + i * 16 + (lane & 15);
                int bytea = (rowa * 128 + kk * 64 + (lane >> 4) * 16) ^ ((rowa & 7) << 4);
                af[i] = *reinterpret_cast<const bf16x8*>(lds + bytea);
                int rowb  = wn * 64 + i * 16 + (lane & 15);
                int byteb = (rowb * 128 + kk * 64 + (lane >> 4) * 16) ^ ((rowb & 7) << 4);
                bfr[i] = *reinterpret_cast<const bf16x8*>(lds + 16384 + byteb);
            }
            #pragma unroll
            for (int i = 0; i < 4; ++i)
                #pragma unroll
                for (int j = 0; j < 4; ++j)
                    acc[i][j] = __builtin_amdgcn_mfma_f32_16x16x32_bf16(af[i], bfr[j], acc[i][j], 0, 0, 0);
        }
    }

    // epilogue: C/D layout col = lane&15, row = (lane>>4)*4 + r
    #pragma unroll
    for (int i = 0; i < 4; ++i) {
        #pragma unroll
        for (int j = 0; j < 4; ++j) {
            #pragma unroll
            for (int r = 0; r < 4; ++r) {
                int row = mbase + wm * 64 + i * 16 + (lane >> 4) * 4 + r;
                int col = nbase + wn * 64 + j * 16 + (lane & 15);
                float cval = acc[i][j][r];
                if (MODE == 0) {
                    Cout[(size_t)row * N + col] = cval;
                } else {
                    int b = row >> 11, t = row & 2047;
                    int d = col & 63;
                    if (col < 1024) {
                        int h = col >> 6;
                        Qo[((size_t)(b * NH + h) * T_ + t) * HD + d] = (bf16_t)(cval * 0.125f);
                    } else if (col < 2048) {
                        int h = (col - 1024) >> 6;
                        Ko[((size_t)(b * NH + h) * T_ + t) * HD + d] = (bf16_t)cval;
                    } else {
                        int h = (col - 2048) >> 6;
                        Vt[((size_t)(b * NH + h) * HD + d) * T_ + t] = (bf16_t)cval;
                    }
                }
            }
        }
    }
}

// ---------------- flash attention: Q[B,H,T,D] (pre-scaled), K[B,H,T,D], Vt[B,H,D,T] ----------------
// block = 256 (4 waves), each wave owns 16 q rows; KV tile = 64
__global__ __launch_bounds__(256) void attn_kernel(
    const bf16_t* __restrict__ Q, const bf16_t* __restrict__ K,
    const bf16_t* __restrict__ Vt, bf16_t* __restrict__ out)
{
    __shared__ __align__(16) char plds[4 * 2048];  // per-wave 16x64 bf16
    const int lane  = threadIdx.x & 63;
    const int wid   = threadIdx.x >> 6;
    const int qtile = blockIdx.x;       // 0..31
    const int bh    = blockIdx.y;       // 0..63
    const int b     = bh >> 4, h = bh & 15;

    const int qbase = qtile * 64 + wid * 16;
    const bf16_t* Qh = Q  + (size_t)bh * T_ * HD;
    const bf16_t* Kh = K  + (size_t)bh * T_ * HD;
    const bf16_t* Vh = Vt + (size_t)bh * HD * T_;

    // Q fragments (A-operand): row = lane&15, d = kk*32 + (lane>>4)*8 + j
    bf16x8 qf[2];
    #pragma unroll
    for (int kk = 0; kk < 2; ++kk)
        qf[kk] = *reinterpret_cast<const bf16x8*>(
            Qh + (size_t)(qbase + (lane & 15)) * HD + kk * 32 + (lane >> 4) * 8);

    f32x4 acc_o[4] = {};
    float m_r[4], l_r[4];
    #pragma unroll
    for (int r = 0; r < 4; ++r) { m_r[r] = -1e30f; l_r[r] = 0.f; }

    char* myp = plds + wid * 2048;
    const int kv_end = ((qbase + 16 + 63) >> 6) << 6;   // per-wave causal bound

    for (int kv0 = 0; kv0 < kv_end; kv0 += 64) {
        // S = Q K^T : 4 kv-subtiles of 16
        f32x4 s[4];
        #pragma unroll
        for (int t = 0; t < 4; ++t) {
            f32x4 a = {};
            #pragma unroll
            for (int kk = 0; kk < 2; ++kk) {
                bf16x8 kf = *reinterpret_cast<const bf16x8*>(
                    Kh + (size_t)(kv0 + t * 16 + (lane & 15)) * HD + kk * 32 + (lane >> 4) * 8);
                a = __builtin_amdgcn_mfma_f32_16x16x32_bf16(qf[kk], kf, a, 0, 0, 0);
            }
            s[t] = a;
        }
        // causal mask (only when tile can cross diagonal)
        const int qrow0  = qbase + (lane >> 4) * 4;
        const int kvcol0 = kv0 + (lane & 15);
        if (kv0 + 63 > qbase) {
            #pragma unroll
            for (int t = 0; t < 4; ++t)
                #pragma unroll
                for (int r = 0; r < 4; ++r)
                    if (kvcol0 + t * 16 > qrow0 + r) s[t][r] = -1e30f;
        }
        // row max (16-lane butterfly within col-groups)
        float alpha[4];
        #pragma unroll
        for (int r = 0; r < 4; ++r) {
            float v = fmaxf(fmaxf(s[0][r], s[1][r]), fmaxf(s[2][r], s[3][r]));
            #pragma unroll
            for (int off = 1; off < 16; off <<= 1)
                v = fmaxf(v, __shfl_xor(v, off, 64));
            float mn = fmaxf(m_r[r], v);
            alpha[r] = __expf(m_r[r] - mn);
            m_r[r] = mn;
        }
        // P = exp(S - m): write bf16 to swizzled LDS, accumulate row sums
        float rsum[4] = {0.f, 0.f, 0.f, 0.f};
        #pragma unroll
        for (int t = 0; t < 4; ++t) {
            #pragma unroll
            for (int r = 0; r < 4; ++r) {
                float p = __expf(s[t][r] - m_r[r]);
                rsum[r] += p;
                int row  = (lane >> 4) * 4 + r;
                int col  = t * 16 + (lane & 15);
                int byte = (row * 128 + col * 2) ^ ((row & 7) << 4);
                *reinterpret_cast<bf16_t*>(myp + byte) = (bf16_t)p;
            }
        }
        #pragma unroll
        for (int r = 0; r < 4; ++r) {
            float v = rsum[r];
            #pragma unroll
            for (int off = 1; off < 16; off <<= 1)
                v += __shfl_xor(v, off, 64);
            l_r[r] = l_r[r] * alpha[r] + v;
        }
        // rescale O
        #pragma unroll
        for (int nf = 0; nf < 4; ++nf)
            #pragma unroll
            for (int r = 0; r < 4; ++r)
                acc_o[nf][r] *= alpha[r];
        // P: LDS roundtrip (C-layout -> A-fragment layout), intra-wave only
        asm volatile("s_waitcnt lgkmcnt(0)" ::: "memory");
        __builtin_amdgcn_sched_barrier(0);
        bf16x8 pf[2];
        #pragma unroll
        for (int kk = 0; kk < 2; ++kk) {
            int row  = lane & 15;
            int byte = (row * 128 + kk * 64 + (lane >> 4) * 16) ^ ((row & 7) << 4);
            pf[kk] = *reinterpret_cast<const bf16x8*>(myp + byte);
        }
        // O += P V  (V read from transposed Vt: contiguous along kv)
        #pragma unroll
        for (int nf = 0; nf < 4; ++nf) {
            #pragma unroll
            for (int kk = 0; kk < 2; ++kk) {
                bf16x8 vf = *reinterpret_cast<const bf16x8*>(
                    Vh + (size_t)(nf * 16 + (lane & 15)) * T_ + kv0 + kk * 32 + (lane >> 4) * 8);
                acc_o[nf] = __builtin_amdgcn_mfma_f32_16x16x32_bf16(pf[kk], vf, acc_o[nf], 0, 0, 0);
            }
        }
    }
    // write out[b, t, h*64 + d] = O / l
    #pragma unroll
    for (int nf = 0; nf < 4; ++nf) {
        #pragma unroll
        for (int r = 0; r < 4; ++r) {
            int t = qbase + (lane >> 4) * 4 + r;
            int d = nf * 16 + (lane & 15);
            out[(size_t)(b * T_ + t) * C_ + h * HD + d] = (bf16_t)(acc_o[nf][r] * (1.f / l_r[r]));
        }
    }
}

// ---------------- launch ----------------
extern "C" void kernel_launch(void* const* d_in, const int* in_sizes, int n_in,
                              void* d_out, int out_size, void* d_ws, size_t ws_size,
                              hipStream_t stream) {
    const float* x      = (const float*)d_in[0];
    const float* w_qkv  = (const float*)d_in[1];
    const float* w_proj = (const float*)d_in[2];
    float* out = (float*)d_out;

    char* ws = (char*)d_ws;
    bf16_t* xb     = (bf16_t*)(ws);                  // 16,777,216 B
    bf16_t* wqkvT  = (bf16_t*)(ws + 16777216);       //  6,291,456 B
    bf16_t* wprojT = (bf16_t*)(ws + 23068672);       //  2,097,152 B
    bf16_t* Qb     = (bf16_t*)(ws + 25165824);       // 16,777,216 B
    bf16_t* Kb     = (bf16_t*)(ws + 41943040);       // 16,777,216 B
    bf16_t* Vtb    = (bf16_t*)(ws + 58720256);       // 16,777,216 B
    bf16_t* attnb  = (bf16_t*)(ws + 75497472);       // 16,777,216 B -> total 92,274,688 B

    conv_x_kernel<<<2048, 256, 0, stream>>>(x, xb, (B_ * T_ * C_) / 4);
    transpose_w_kernel<<<dim3(3 * C_ / 32, C_ / 32), dim3(32, 8), 0, stream>>>(w_qkv, wqkvT, C_, 3 * C_);
    transpose_w_kernel<<<dim3(C_ / 32, C_ / 32), dim3(32, 8), 0, stream>>>(w_proj, wprojT, C_, C_);

    gemm_bt_kernel<1><<<dim3(3 * C_ / BN, M_TOT / BM), 256, 0, stream>>>(
        xb, wqkvT, nullptr, Qb, Kb, Vtb, M_TOT, 3 * C_, C_);

    attn_kernel<<<dim3(T_ / 64, B_ * NH), 256, 0, stream>>>(Qb, Kb, Vtb, attnb);

    gemm_bt_kernel<0><<<dim3(C_ / BN, M_TOT / BM), 256, 0, stream>>>(
        attnb, wprojT, out, nullptr, nullptr, nullptr, M_TOT, C_, C_);
}

// Round 2
// 284.403 us; speedup vs baseline: 2.0763x; 2.0763x over previous
//
#include <hip/hip_runtime.h>
#include <hip/hip_bf16.h>
#include <stdint.h>

typedef __bf16 bf16_t;
typedef __bf16 bf16x8 __attribute__((ext_vector_type(8)));
typedef float  f32x4  __attribute__((ext_vector_type(4)));

#define B_    4
#define T_    2048
#define C_    1024
#define NH    16
#define HD    64
#define M_TOT (B_ * T_)   // 8192

// async global -> LDS, 16B per lane (dest must be wave-uniform base + lane*16)
__device__ __forceinline__ void gload16(const void* g, void* l) {
    __builtin_amdgcn_global_load_lds(
        (const __attribute__((address_space(1))) uint32_t*)g,
        (__attribute__((address_space(3))) uint32_t*)l, 16, 0, 0);
}

// ---------------- convert x (fp32) -> bf16, flat ----------------
__global__ void conv_x_kernel(const float* __restrict__ x, bf16_t* __restrict__ xb, int n4) {
    int i = blockIdx.x * blockDim.x + threadIdx.x;
    int stride = gridDim.x * blockDim.x;
    for (; i < n4; i += stride) {
        float4 v = reinterpret_cast<const float4*>(x)[i];
        union { bf16_t h[4]; uint2 u; } p;
        p.h[0] = (bf16_t)v.x; p.h[1] = (bf16_t)v.y;
        p.h[2] = (bf16_t)v.z; p.h[3] = (bf16_t)v.w;
        reinterpret_cast<uint2*>(xb)[i] = p.u;
    }
}

// ---------------- transpose + convert: w[K][N] fp32 -> wt[N][K] bf16 ----------------
__global__ void transpose_w_kernel(const float* __restrict__ w, bf16_t* __restrict__ wt,
                                   int K, int N) {
    __shared__ float tile[32][33];
    int n0 = blockIdx.x * 32, k0 = blockIdx.y * 32;
    int tx = threadIdx.x, ty = threadIdx.y;
    #pragma unroll
    for (int i = 0; i < 32; i += 8)
        tile[ty + i][tx] = w[(size_t)(k0 + ty + i) * N + n0 + tx];
    __syncthreads();
    #pragma unroll
    for (int i = 0; i < 32; i += 8)
        wt[(size_t)(n0 + ty + i) * K + k0 + tx] = (bf16_t)tile[tx][ty + i];
}

// ---------------- GEMM: C[M][N] = A[M][K](bf16) * Bt[N][K](bf16)^T ----------------
// MODE 0: write fp32 C to Cout
// MODE 1: QKV epilogue -> Q (scaled 1/8*log2e) [B,H,T,D], K [B,H,T,D], V transposed [B,H,D,T]
#define BM 128
#define BN 128
#define BKK 64

#define QSCALE 0.18033688011112042f   // (1/8) * log2(e)

template<int MODE>
__global__ __launch_bounds__(256) void gemm_bt_kernel(
    const bf16_t* __restrict__ A, const bf16_t* __restrict__ Bt,
    float* __restrict__ Cout,
    bf16_t* __restrict__ Qo, bf16_t* __restrict__ Ko, bf16_t* __restrict__ Vt,
    int M, int N, int K)
{
    __shared__ __align__(16) char lds[BM * 128 + BN * 128];  // A: 16KB, B: 16KB (BK=64 bf16)
    const int tid  = threadIdx.x;
    const int lane = tid & 63;
    const int wid  = tid >> 6;
    const int wm   = wid >> 1, wn = wid & 1;
    const int mbase = blockIdx.y * BM;
    const int nbase = blockIdx.x * BN;

    f32x4 acc[4][4] = {};

    for (int k0 = 0; k0 < K; k0 += BKK) {
        __syncthreads();   // protect prev-iter LDS reads before overwrite
        // stage A and B tiles via global_load_lds: linear LDS dest,
        // source column pre-XOR-swizzled so reads at byte^((row&7)<<4) are conflict-free
        #pragma unroll
        for (int c = 0; c < 4; ++c) {
            int li  = tid + c * 256;       // 0..1023 chunks of 16B
            int row = li >> 3;             // 0..127
            int sw  = (li & 7) ^ (row & 7);
            gload16(A  + (size_t)(mbase + row) * K + k0 + sw * 8, lds + li * 16);
            gload16(Bt + (size_t)(nbase + row) * K + k0 + sw * 8, lds + 16384 + li * 16);
        }
        __syncthreads();   // implies vmcnt(0): staged data visible
        #pragma unroll
        for (int kk = 0; kk < 2; ++kk) {
            bf16x8 af[4], bfr[4];
            #pragma unroll
            for (int i = 0; i < 4; ++i) {
                int rowa  = wm * 64 + i * 16 + (lane & 15);
                int bytea = (rowa * 128 + kk * 64 + (lane >> 4) * 16) ^ ((rowa & 7) << 4);
                af[i] = *reinterpret_cast<const bf16x8*>(lds + bytea);
                int rowb  = wn * 64 + i * 16 + (lane & 15);
                int byteb = (rowb * 128 + kk * 64 + (lane >> 4) * 16) ^ ((rowb & 7) << 4);
                bfr[i] = *reinterpret_cast<const bf16x8*>(lds + 16384 + byteb);
            }
            #pragma unroll
            for (int i = 0; i < 4; ++i)
                #pragma unroll
                for (int j = 0; j < 4; ++j)
                    acc[i][j] = __builtin_amdgcn_mfma_f32_16x16x32_bf16(af[i], bfr[j], acc[i][j], 0, 0, 0);
        }
    }

    // epilogue: C/D layout col = lane&15, row = (lane>>4)*4 + r
    #pragma unroll
    for (int i = 0; i < 4; ++i) {
        #pragma unroll
        for (int j = 0; j < 4; ++j) {
            #pragma unroll
            for (int r = 0; r < 4; ++r) {
                int row = mbase + wm * 64 + i * 16 + (lane >> 4) * 4 + r;
                int col = nbase + wn * 64 + j * 16 + (lane & 15);
                float cval = acc[i][j][r];
                if (MODE == 0) {
                    Cout[(size_t)row * N + col] = cval;
                } else {
                    int b = row >> 11, t = row & 2047;
                    int d = col & 63;
                    if (col < 1024) {
                        int h = col >> 6;
                        Qo[((size_t)(b * NH + h) * T_ + t) * HD + d] = (bf16_t)(cval * QSCALE);
                    } else if (col < 2048) {
                        int h = (col - 1024) >> 6;
                        Ko[((size_t)(b * NH + h) * T_ + t) * HD + d] = (bf16_t)cval;
                    } else {
                        int h = (col - 2048) >> 6;
                        Vt[((size_t)(b * NH + h) * HD + d) * T_ + t] = (bf16_t)cval;
                    }
                }
            }
        }
    }
}

// ---------------- flash attention ----------------
// Q[B,H,T,D] (pre-scaled by 1/8*log2e), K[B,H,T,D], Vt[B,H,D,T].
// Grid (16, B*H). Block = 4 waves. Block j handles q-tiles (31-j) and (j):
// (32-j) + (j+1) = 33 KV-tile iterations per block -> perfectly balanced.
// K/V tiles (64x64 bf16, 8KB each) staged cooperatively in double-buffered LDS
// via global_load_lds with inverse-source-swizzle; counted vmcnt keeps prefetch in flight.
__global__ __launch_bounds__(256) void attn_kernel(
    const bf16_t* __restrict__ Q, const bf16_t* __restrict__ K,
    const bf16_t* __restrict__ Vt, bf16_t* __restrict__ out)
{
    __shared__ __align__(16) char kvbuf[2][16384];   // [buf][ K 8KB | V 8KB ]
    __shared__ __align__(16) char plds[4][2048];     // per-wave 16x64 bf16 P patch
    const int tid  = threadIdx.x;
    const int lane = tid & 63;
    const int wid  = tid >> 6;
    const int j    = blockIdx.x;        // 0..15
    const int bh   = blockIdx.y;        // 0..63
    const int b    = bh >> 4, h = bh & 15;

    const bf16_t* Qh = Q  + (size_t)bh * T_ * HD;
    const bf16_t* Kh = K  + (size_t)bh * T_ * HD;
    const bf16_t* Vh = Vt + (size_t)bh * HD * T_;
    char* myp = plds[wid];

#define STAGE(buf, kv0) do {                                                     \
        _Pragma("unroll")                                                        \
        for (int c = 0; c < 2; ++c) {                                            \
            int li  = tid + c * 256;        /* 0..511 chunks of 16B */           \
            int row = li >> 3;              /* 0..63 */                          \
            int sw  = (li & 7) ^ (row & 7);                                      \
            gload16(Kh + (size_t)((kv0) + row) * HD + sw * 8, (char*)(buf) + li * 16);          \
            gload16(Vh + (size_t)row * T_ + (kv0) + sw * 8, (char*)(buf) + 8192 + li * 16);     \
        } } while (0)

    #pragma unroll 1
    for (int part = 0; part < 2; ++part) {
        const int qtile = part ? j : (31 - j);
        const int nt    = qtile + 1;
        const int qbase = qtile * 64 + wid * 16;

        // Q fragments (A-operand): row = lane&15, k = kk*32 + (lane>>4)*8 + jj
        bf16x8 qf[2];
        #pragma unroll
        for (int kk = 0; kk < 2; ++kk)
            qf[kk] = *reinterpret_cast<const bf16x8*>(
                Qh + (size_t)(qbase + (lane & 15)) * HD + kk * 32 + (lane >> 4) * 8);

        f32x4 acc_o[4] = {};
        float m_r[4], l_r[4];
        #pragma unroll
        for (int r = 0; r < 4; ++r) { m_r[r] = -1e30f; l_r[r] = 0.f; }

        STAGE(kvbuf[0], 0);
        int cur = 0;
        for (int it = 0; it < nt; ++it) {
            const int kv0 = it * 64;
            if (it + 1 < nt) {
                STAGE(kvbuf[cur ^ 1], (it + 1) * 64);
                asm volatile("s_waitcnt vmcnt(4)" ::: "memory");  // wait current tile only
            } else {
                asm volatile("s_waitcnt vmcnt(0)" ::: "memory");
            }
            __builtin_amdgcn_s_barrier();
            __builtin_amdgcn_sched_barrier(0);
            const char* Kl = kvbuf[cur];
            const char* Vl = kvbuf[cur] + 8192;

            // S = Q K^T : 4 kv-subtiles of 16
            f32x4 s4[4];
            #pragma unroll
            for (int t = 0; t < 4; ++t) {
                f32x4 a = {};
                #pragma unroll
                for (int kk = 0; kk < 2; ++kk) {
                    int row  = t * 16 + (lane & 15);
                    int byte = (row * 128 + kk * 64 + (lane >> 4) * 16) ^ ((row & 7) << 4);
                    bf16x8 kf = *reinterpret_cast<const bf16x8*>(Kl + byte);
                    a = __builtin_amdgcn_mfma_f32_16x16x32_bf16(qf[kk], kf, a, 0, 0, 0);
                }
                s4[t] = a;
            }
            // causal mask only on the last (diagonal) tile
            if (it == nt - 1) {
                const int qrow0  = qbase + (lane >> 4) * 4;
                const int kvcol0 = kv0 + (lane & 15);
                #pragma unroll
                for (int t = 0; t < 4; ++t)
                    #pragma unroll
                    for (int r = 0; r < 4; ++r)
                        if (kvcol0 + t * 16 > qrow0 + r) s4[t][r] = -1e30f;
            }
            // online softmax (exp2 domain; scores already scaled by log2e/8)
            float alpha[4];
            #pragma unroll
            for (int r = 0; r < 4; ++r) {
                float v = fmaxf(fmaxf(s4[0][r], s4[1][r]), fmaxf(s4[2][r], s4[3][r]));
                #pragma unroll
                for (int off = 1; off < 16; off <<= 1)
                    v = fmaxf(v, __shfl_xor(v, off, 64));
                float mn = fmaxf(m_r[r], v);
                alpha[r] = exp2f(m_r[r] - mn);
                m_r[r] = mn;
            }
            float rsum[4] = {0.f, 0.f, 0.f, 0.f};
            #pragma unroll
            for (int t = 0; t < 4; ++t) {
                #pragma unroll
                for (int r = 0; r < 4; ++r) {
                    float p = exp2f(s4[t][r] - m_r[r]);
                    rsum[r] += p;
                    int row  = (lane >> 4) * 4 + r;
                    int col  = t * 16 + (lane & 15);
                    int byte = (row * 128 + col * 2) ^ ((row & 7) << 4);
                    *reinterpret_cast<bf16_t*>(myp + byte) = (bf16_t)p;
                }
            }
            #pragma unroll
            for (int r = 0; r < 4; ++r) {
                float v = rsum[r];
                #pragma unroll
                for (int off = 1; off < 16; off <<= 1)
                    v += __shfl_xor(v, off, 64);
                l_r[r] = l_r[r] * alpha[r] + v;
            }
            #pragma unroll
            for (int nf = 0; nf < 4; ++nf)
                #pragma unroll
                for (int r = 0; r < 4; ++r)
                    acc_o[nf][r] *= alpha[r];
            // P roundtrip (C-layout -> A-frag layout), intra-wave
            asm volatile("s_waitcnt lgkmcnt(0)" ::: "memory");
            __builtin_amdgcn_sched_barrier(0);
            bf16x8 pf[2];
            #pragma unroll
            for (int kk = 0; kk < 2; ++kk) {
                int row  = lane & 15;
                int byte = (row * 128 + kk * 64 + (lane >> 4) * 16) ^ ((row & 7) << 4);
                pf[kk] = *reinterpret_cast<const bf16x8*>(myp + byte);
            }
            // O += P V  from staged V tile [d][kv]
            #pragma unroll
            for (int nf = 0; nf < 4; ++nf) {
                #pragma unroll
                for (int kk = 0; kk < 2; ++kk) {
                    int row  = nf * 16 + (lane & 15);
                    int byte = (row * 128 + kk * 64 + (lane >> 4) * 16) ^ ((row & 7) << 4);
                    bf16x8 vf = *reinterpret_cast<const bf16x8*>(Vl + byte);
                    acc_o[nf] = __builtin_amdgcn_mfma_f32_16x16x32_bf16(pf[kk], vf, acc_o[nf], 0, 0, 0);
                }
            }
            __syncthreads();   // all waves done reading buf[cur] before it is re-staged
            cur ^= 1;
        }
        // write out[b, t, h*64 + d] = O / l
        #pragma unroll
        for (int nf = 0; nf < 4; ++nf) {
            #pragma unroll
            for (int r = 0; r < 4; ++r) {
                int t = qbase + (lane >> 4) * 4 + r;
                int d = nf * 16 + (lane & 15);
                out[(size_t)(b * T_ + t) * C_ + h * HD + d] = (bf16_t)(acc_o[nf][r] * (1.f / l_r[r]));
            }
        }
    }
#undef STAGE
}

// ---------------- launch ----------------
extern "C" void kernel_launch(void* const* d_in, const int* in_sizes, int n_in,
                              void* d_out, int out_size, void* d_ws, size_t ws_size,
                              hipStream_t stream) {
    const float* x      = (const float*)d_in[0];
    const float* w_qkv  = (const float*)d_in[1];
    const float* w_proj = (const float*)d_in[2];
    float* out = (float*)d_out;

    char* ws = (char*)d_ws;
    bf16_t* xb     = (bf16_t*)(ws);                  // 16,777,216 B
    bf16_t* wqkvT  = (bf16_t*)(ws + 16777216);       //  6,291,456 B
    bf16_t* wprojT = (bf16_t*)(ws + 23068672);       //  2,097,152 B
    bf16_t* Qb     = (bf16_t*)(ws + 25165824);       // 16,777,216 B
    bf16_t* Kb     = (bf16_t*)(ws + 41943040);       // 16,777,216 B
    bf16_t* Vtb    = (bf16_t*)(ws + 58720256);       // 16,777,216 B
    bf16_t* attnb  = (bf16_t*)(ws + 75497472);       // 16,777,216 B -> total 92,274,688 B

    conv_x_kernel<<<2048, 256, 0, stream>>>(x, xb, (B_ * T_ * C_) / 4);
    transpose_w_kernel<<<dim3(3 * C_ / 32, C_ / 32), dim3(32, 8), 0, stream>>>(w_qkv, wqkvT, C_, 3 * C_);
    transpose_w_kernel<<<dim3(C_ / 32, C_ / 32), dim3(32, 8), 0, stream>>>(w_proj, wprojT, C_, C_);

    gemm_bt_kernel<1><<<dim3(3 * C_ / BN, M_TOT / BM), 256, 0, stream>>>(
        xb, wqkvT, nullptr, Qb, Kb, Vtb, M_TOT, 3 * C_, C_);

    attn_kernel<<<dim3(16, B_ * NH), 256, 0, stream>>>(Qb, Kb, Vtb, attnb);

    gemm_bt_kernel<0><<<dim3(C_ / BN, M_TOT / BM), 256, 0, stream>>>(
        attnb, wprojT, out, nullptr, nullptr, nullptr, M_TOT, C_, C_);
}

// Round 3
// 228.008 us; speedup vs baseline: 2.5898x; 1.2473x over previous
//
#include <hip/hip_runtime.h>
#include <hip/hip_bf16.h>
#include <stdint.h>

typedef __bf16 bf16_t;
typedef __bf16 bf16x4 __attribute__((ext_vector_type(4)));
typedef __bf16 bf16x8 __attribute__((ext_vector_type(8)));
typedef float  f32x4  __attribute__((ext_vector_type(4)));

#define B_    4
#define T_    2048
#define C_    1024
#define NH    16
#define HD    64
#define M_TOT (B_ * T_)   // 8192

// async global -> LDS, 16B per lane (dest must be wave-uniform base + lane*16)
__device__ __forceinline__ void gload16(const void* g, void* l) {
    __builtin_amdgcn_global_load_lds(
        (const __attribute__((address_space(1))) uint32_t*)g,
        (__attribute__((address_space(3))) uint32_t*)l, 16, 0, 0);
}

// ---------------- convert x (fp32) -> bf16, flat ----------------
__global__ void conv_x_kernel(const float* __restrict__ x, bf16_t* __restrict__ xb, int n4) {
    int i = blockIdx.x * blockDim.x + threadIdx.x;
    int stride = gridDim.x * blockDim.x;
    for (; i < n4; i += stride) {
        float4 v = reinterpret_cast<const float4*>(x)[i];
        union { bf16_t h[4]; uint2 u; } p;
        p.h[0] = (bf16_t)v.x; p.h[1] = (bf16_t)v.y;
        p.h[2] = (bf16_t)v.z; p.h[3] = (bf16_t)v.w;
        reinterpret_cast<uint2*>(xb)[i] = p.u;
    }
}

// ---------------- transpose + convert: w[K][N] fp32 -> wt[N][K] bf16 ----------------
__global__ void transpose_w_kernel(const float* __restrict__ w, bf16_t* __restrict__ wt,
                                   int K, int N) {
    __shared__ float tile[32][33];
    int n0 = blockIdx.x * 32, k0 = blockIdx.y * 32;
    int tx = threadIdx.x, ty = threadIdx.y;
    #pragma unroll
    for (int i = 0; i < 32; i += 8)
        tile[ty + i][tx] = w[(size_t)(k0 + ty + i) * N + n0 + tx];
    __syncthreads();
    #pragma unroll
    for (int i = 0; i < 32; i += 8)
        wt[(size_t)(n0 + ty + i) * K + k0 + tx] = (bf16_t)tile[tx][ty + i];
}

// ---------------- GEMM: C[M][N] = A[M][K](bf16) * Bt[N][K](bf16)^T ----------------
#define BM 128
#define BN 128
#define BKK 64

#define QSCALE 0.18033688011112042f   // (1/8) * log2(e)

template<int MODE>
__global__ __launch_bounds__(256) void gemm_bt_kernel(
    const bf16_t* __restrict__ A, const bf16_t* __restrict__ Bt,
    float* __restrict__ Cout,
    bf16_t* __restrict__ Qo, bf16_t* __restrict__ Ko, bf16_t* __restrict__ Vt,
    int M, int N, int K)
{
    __shared__ __align__(16) char lds[BM * 128 + BN * 128];
    const int tid  = threadIdx.x;
    const int lane = tid & 63;
    const int wid  = tid >> 6;
    const int wm   = wid >> 1, wn = wid & 1;
    const int mbase = blockIdx.y * BM;
    const int nbase = blockIdx.x * BN;

    f32x4 acc[4][4] = {};

    for (int k0 = 0; k0 < K; k0 += BKK) {
        __syncthreads();
        #pragma unroll
        for (int c = 0; c < 4; ++c) {
            int li  = tid + c * 256;
            int row = li >> 3;
            int sw  = (li & 7) ^ (row & 7);
            gload16(A  + (size_t)(mbase + row) * K + k0 + sw * 8, lds + li * 16);
            gload16(Bt + (size_t)(nbase + row) * K + k0 + sw * 8, lds + 16384 + li * 16);
        }
        __syncthreads();
        #pragma unroll
        for (int kk = 0; kk < 2; ++kk) {
            bf16x8 af[4], bfr[4];
            #pragma unroll
            for (int i = 0; i < 4; ++i) {
                int rowa  = wm * 64 + i * 16 + (lane & 15);
                int bytea = (rowa * 128 + kk * 64 + (lane >> 4) * 16) ^ ((rowa & 7) << 4);
                af[i] = *reinterpret_cast<const bf16x8*>(lds + bytea);
                int rowb  = wn * 64 + i * 16 + (lane & 15);
                int byteb = (rowb * 128 + kk * 64 + (lane >> 4) * 16) ^ ((rowb & 7) << 4);
                bfr[i] = *reinterpret_cast<const bf16x8*>(lds + 16384 + byteb);
            }
            #pragma unroll
            for (int i = 0; i < 4; ++i)
                #pragma unroll
                for (int j = 0; j < 4; ++j)
                    acc[i][j] = __builtin_amdgcn_mfma_f32_16x16x32_bf16(af[i], bfr[j], acc[i][j], 0, 0, 0);
        }
    }

    #pragma unroll
    for (int i = 0; i < 4; ++i) {
        #pragma unroll
        for (int j = 0; j < 4; ++j) {
            #pragma unroll
            for (int r = 0; r < 4; ++r) {
                int row = mbase + wm * 64 + i * 16 + (lane >> 4) * 4 + r;
                int col = nbase + wn * 64 + j * 16 + (lane & 15);
                float cval = acc[i][j][r];
                if (MODE == 0) {
                    Cout[(size_t)row * N + col] = cval;
                } else {
                    int b = row >> 11, t = row & 2047;
                    int d = col & 63;
                    if (col < 1024) {
                        int h = col >> 6;
                        Qo[((size_t)(b * NH + h) * T_ + t) * HD + d] = (bf16_t)(cval * QSCALE);
                    } else if (col < 2048) {
                        int h = (col - 1024) >> 6;
                        Ko[((size_t)(b * NH + h) * T_ + t) * HD + d] = (bf16_t)cval;
                    } else {
                        int h = (col - 2048) >> 6;
                        Vt[((size_t)(b * NH + h) * HD + d) * T_ + t] = (bf16_t)cval;
                    }
                }
            }
        }
    }
}

// ---------------- flash attention (swapped-operand, in-register softmax) ----------------
// Q[B,H,T,D] (pre-scaled by 1/8*log2e), K[B,H,T,D], Vt[B,H,D,T].
// 1D grid 1024, XCD-chunked: all 16 q-tile blocks of a head on one XCD.
// Block j handles q-tiles (31-j) and (j): 33 KV-iters -> perfectly balanced.
// S^T = mfma(K,Q): lane owns q-row = lane&15; kv = 16t + 4*(lane>>4) + r.
// O^T = mfma(V^T, P^T): accT col = q = lane&15, row-block = d.
__global__ __launch_bounds__(256) void attn_kernel(
    const bf16_t* __restrict__ Q, const bf16_t* __restrict__ K,
    const bf16_t* __restrict__ Vt, bf16_t* __restrict__ out)
{
    __shared__ __align__(16) char kvbuf[2][16384];   // [buf][ K 8KB | V 8KB ]
    __shared__ __align__(16) char plds[4][2048];     // per-wave 16q x 64kv bf16 P^T patch
    const int tid  = threadIdx.x;
    const int lane = tid & 63;
    const int wid  = tid >> 6;
    const int g    = lane >> 4;         // lane group 0..3
    const int q16  = lane & 15;         // q-row within wave tile

    // XCD-aware remap: xcd = id&7 (assumed round-robin), 8 heads per XCD
    const int id  = blockIdx.x;          // 0..1023
    const int xcd = id & 7;
    const int k2  = id >> 3;             // 0..127
    const int bh  = xcd * 8 + (k2 >> 4); // 0..63
    const int j   = k2 & 15;             // 0..15
    const int b   = bh >> 4, h = bh & 15;

    const bf16_t* Qh = Q  + (size_t)bh * T_ * HD;
    const bf16_t* Kh = K  + (size_t)bh * T_ * HD;
    const bf16_t* Vh = Vt + (size_t)bh * HD * T_;
    char* myp = plds[wid];
    const int pswz = (q16 & 7) << 4;

#define STAGE(buf, kv0) do {                                                     \
        _Pragma("unroll")                                                        \
        for (int c = 0; c < 2; ++c) {                                            \
            int li  = tid + c * 256;                                             \
            int row = li >> 3;                                                   \
            int sw  = (li & 7) ^ (row & 7);                                      \
            gload16(Kh + (size_t)((kv0) + row) * HD + sw * 8, (char*)(buf) + li * 16);          \
            gload16(Vh + (size_t)row * T_ + (kv0) + sw * 8, (char*)(buf) + 8192 + li * 16);     \
        } } while (0)

    #pragma unroll 1
    for (int part = 0; part < 2; ++part) {
        const int qtile = part ? j : (31 - j);
        const int nt    = qtile + 1;
        const int qbase = qtile * 64 + wid * 16;
        const int qg    = qbase + q16;   // this lane's global q row

        // Q fragments (B-operand): col = q16, k = kk*32 + g*8 + jj
        bf16x8 qf[2];
        #pragma unroll
        for (int kk = 0; kk < 2; ++kk)
            qf[kk] = *reinterpret_cast<const bf16x8*>(
                Qh + (size_t)qg * HD + kk * 32 + g * 8);

        f32x4 accT[4] = {};   // O^T: accT[nf] covers d = nf*16 + g*4 + r, col q16
        float m = -1e30f, l = 0.f;

        STAGE(kvbuf[0], 0);
        int cur = 0;
        for (int it = 0; it < nt; ++it) {
            const int kv0 = it * 64;
            if (it + 1 < nt) {
                STAGE(kvbuf[cur ^ 1], (it + 1) * 64);
                asm volatile("s_waitcnt vmcnt(4)" ::: "memory");
            } else {
                asm volatile("s_waitcnt vmcnt(0)" ::: "memory");
            }
            __builtin_amdgcn_s_barrier();
            __builtin_amdgcn_sched_barrier(0);
            const char* Kl = kvbuf[cur];
            const char* Vl = kvbuf[cur] + 8192;

            // S^T = K Q^T : lane holds kv = 16t + 4g + r for q-row q16
            f32x4 s4[4];
            __builtin_amdgcn_s_setprio(1);
            #pragma unroll
            for (int t = 0; t < 4; ++t) {
                f32x4 a = {};
                #pragma unroll
                for (int kk = 0; kk < 2; ++kk) {
                    int row  = t * 16 + q16;
                    int byte = (row * 128 + kk * 64 + g * 16) ^ ((row & 7) << 4);
                    bf16x8 kf = *reinterpret_cast<const bf16x8*>(Kl + byte);
                    a = __builtin_amdgcn_mfma_f32_16x16x32_bf16(kf, qf[kk], a, 0, 0, 0);
                }
                s4[t] = a;
            }
            __builtin_amdgcn_s_setprio(0);
            // causal mask only on the diagonal tile
            if (it == nt - 1) {
                #pragma unroll
                for (int t = 0; t < 4; ++t)
                    #pragma unroll
                    for (int r = 0; r < 4; ++r)
                        if (kv0 + t * 16 + g * 4 + r > qg) s4[t][r] = -1e30f;
            }
            // tile max (in-register tree + 2 shfl)
            float mt = fmaxf(fmaxf(s4[0][0], s4[0][1]), fmaxf(s4[0][2], s4[0][3]));
            #pragma unroll
            for (int t = 1; t < 4; ++t)
                mt = fmaxf(mt, fmaxf(fmaxf(s4[t][0], s4[t][1]), fmaxf(s4[t][2], s4[t][3])));
            mt = fmaxf(mt, __shfl_xor(mt, 16, 64));
            mt = fmaxf(mt, __shfl_xor(mt, 32, 64));
            // defer-max: rescale only if some row grew by > 8 (log2 domain)
            if (!__all(mt <= m + 8.f)) {
                float mn = fmaxf(m, mt);
                float alpha = exp2f(m - mn);
                m = mn;
                l *= alpha;
                #pragma unroll
                for (int nf = 0; nf < 4; ++nf)
                    #pragma unroll
                    for (int r = 0; r < 4; ++r)
                        accT[nf][r] *= alpha;
            }
            // P = exp2(S - m), in-register row sum, pack to P^T LDS patch
            float rs = 0.f;
            #pragma unroll
            for (int t = 0; t < 4; ++t) {
                float p0 = exp2f(s4[t][0] - m);
                float p1 = exp2f(s4[t][1] - m);
                float p2 = exp2f(s4[t][2] - m);
                float p3 = exp2f(s4[t][3] - m);
                rs += (p0 + p1) + (p2 + p3);
                bf16x4 pw = { (bf16_t)p0, (bf16_t)p1, (bf16_t)p2, (bf16_t)p3 };
                int byte = (q16 * 128 + t * 32 + g * 8) ^ pswz;
                *reinterpret_cast<bf16x4*>(myp + byte) = pw;
            }
            rs += __shfl_xor(rs, 16, 64);
            rs += __shfl_xor(rs, 32, 64);
            l += rs;
            // P^T roundtrip: read B-fragments (intra-wave)
            asm volatile("s_waitcnt lgkmcnt(0)" ::: "memory");
            __builtin_amdgcn_sched_barrier(0);
            bf16x8 pf[2];
            #pragma unroll
            for (int kk2 = 0; kk2 < 2; ++kk2) {
                int byte = (q16 * 128 + kk2 * 64 + g * 16) ^ pswz;
                pf[kk2] = *reinterpret_cast<const bf16x8*>(myp + byte);
            }
            // O^T += V^T P^T
            __builtin_amdgcn_s_setprio(1);
            #pragma unroll
            for (int nf = 0; nf < 4; ++nf) {
                #pragma unroll
                for (int kk2 = 0; kk2 < 2; ++kk2) {
                    int row  = nf * 16 + q16;
                    int byte = (row * 128 + kk2 * 64 + g * 16) ^ ((row & 7) << 4);
                    bf16x8 vf = *reinterpret_cast<const bf16x8*>(Vl + byte);
                    accT[nf] = __builtin_amdgcn_mfma_f32_16x16x32_bf16(vf, pf[kk2], accT[nf], 0, 0, 0);
                }
            }
            __builtin_amdgcn_s_setprio(0);
            __syncthreads();
            cur ^= 1;
        }
        // write out[b, qg, h*64 + d], d = nf*16 + g*4 + r  (8B packed stores)
        float inv = 1.f / l;
        #pragma unroll
        for (int nf = 0; nf < 4; ++nf) {
            bf16x4 ov = { (bf16_t)(accT[nf][0] * inv), (bf16_t)(accT[nf][1] * inv),
                          (bf16_t)(accT[nf][2] * inv), (bf16_t)(accT[nf][3] * inv) };
            *reinterpret_cast<bf16x4*>(
                out + (size_t)(b * T_ + qg) * C_ + h * HD + nf * 16 + g * 4) = ov;
        }
    }
#undef STAGE
}

// ---------------- launch ----------------
extern "C" void kernel_launch(void* const* d_in, const int* in_sizes, int n_in,
                              void* d_out, int out_size, void* d_ws, size_t ws_size,
                              hipStream_t stream) {
    const float* x      = (const float*)d_in[0];
    const float* w_qkv  = (const float*)d_in[1];
    const float* w_proj = (const float*)d_in[2];
    float* out = (float*)d_out;

    char* ws = (char*)d_ws;
    bf16_t* xb     = (bf16_t*)(ws);                  // 16,777,216 B
    bf16_t* wqkvT  = (bf16_t*)(ws + 16777216);       //  6,291,456 B
    bf16_t* wprojT = (bf16_t*)(ws + 23068672);       //  2,097,152 B
    bf16_t* Qb     = (bf16_t*)(ws + 25165824);       // 16,777,216 B
    bf16_t* Kb     = (bf16_t*)(ws + 41943040);       // 16,777,216 B
    bf16_t* Vtb    = (bf16_t*)(ws + 58720256);       // 16,777,216 B
    bf16_t* attnb  = (bf16_t*)(ws + 75497472);       // 16,777,216 B -> total 92,274,688 B

    conv_x_kernel<<<2048, 256, 0, stream>>>(x, xb, (B_ * T_ * C_) / 4);
    transpose_w_kernel<<<dim3(3 * C_ / 32, C_ / 32), dim3(32, 8), 0, stream>>>(w_qkv, wqkvT, C_, 3 * C_);
    transpose_w_kernel<<<dim3(C_ / 32, C_ / 32), dim3(32, 8), 0, stream>>>(w_proj, wprojT, C_, C_);

    gemm_bt_kernel<1><<<dim3(3 * C_ / BN, M_TOT / BM), 256, 0, stream>>>(
        xb, wqkvT, nullptr, Qb, Kb, Vtb, M_TOT, 3 * C_, C_);

    attn_kernel<<<1024, 256, 0, stream>>>(Qb, Kb, Vtb, attnb);

    gemm_bt_kernel<0><<<dim3(C_ / BN, M_TOT / BM), 256, 0, stream>>>(
        attnb, wprojT, out, nullptr, nullptr, nullptr, M_TOT, C_, C_);
}

// Round 4
// 226.343 us; speedup vs baseline: 2.6089x; 1.0074x over previous
//
#include <hip/hip_runtime.h>
#include <hip/hip_bf16.h>
#include <stdint.h>

typedef __bf16 bf16_t;
typedef __bf16 bf16x4 __attribute__((ext_vector_type(4)));
typedef __bf16 bf16x8 __attribute__((ext_vector_type(8)));
typedef float  f32x4  __attribute__((ext_vector_type(4)));

#define B_    4
#define T_    2048
#define C_    1024
#define NH    16
#define HD    64
#define M_TOT (B_ * T_)   // 8192

// async global -> LDS, 16B per lane (dest must be wave-uniform base + lane*16)
__device__ __forceinline__ void gload16(const void* g, void* l) {
    __builtin_amdgcn_global_load_lds(
        (const __attribute__((address_space(1))) uint32_t*)g,
        (__attribute__((address_space(3))) uint32_t*)l, 16, 0, 0);
}

// ---------------- convert x (fp32) -> bf16, flat ----------------
__global__ void conv_x_kernel(const float* __restrict__ x, bf16_t* __restrict__ xb, int n4) {
    int i = blockIdx.x * blockDim.x + threadIdx.x;
    int stride = gridDim.x * blockDim.x;
    for (; i < n4; i += stride) {
        float4 v = reinterpret_cast<const float4*>(x)[i];
        union { bf16_t h[4]; uint2 u; } p;
        p.h[0] = (bf16_t)v.x; p.h[1] = (bf16_t)v.y;
        p.h[2] = (bf16_t)v.z; p.h[3] = (bf16_t)v.w;
        reinterpret_cast<uint2*>(xb)[i] = p.u;
    }
}

// ---------------- transpose + convert: w[K][N] fp32 -> wt[N][K] bf16 ----------------
__global__ void transpose_w_kernel(const float* __restrict__ w, bf16_t* __restrict__ wt,
                                   int K, int N) {
    __shared__ float tile[32][33];
    int n0 = blockIdx.x * 32, k0 = blockIdx.y * 32;
    int tx = threadIdx.x, ty = threadIdx.y;
    #pragma unroll
    for (int i = 0; i < 32; i += 8)
        tile[ty + i][tx] = w[(size_t)(k0 + ty + i) * N + n0 + tx];
    __syncthreads();
    #pragma unroll
    for (int i = 0; i < 32; i += 8)
        wt[(size_t)(n0 + ty + i) * K + k0 + tx] = (bf16_t)tile[tx][ty + i];
}

#define QSCALE 0.18033688011112042f   // (1/8) * log2(e)

// ---------------- 256x256 8-phase GEMM: C[M][N] = A[M][K](bf16) * Bt[N][K]^T ----------------
// 512 threads = 8 waves (2M x 4N); per-wave output 128x64 (8 mrep x 4 nrep).
// LDS 128KB: buf0{A,B} even K-tiles, buf1{A,B} odd K-tiles, BK=64.
// 8 phases / 2 K-tiles; counted vmcnt(4) only at phase 3/7 end.
#define LA0 0
#define LB0 32768
#define LA1 65536
#define LB1 98304

#define STAGEA8(base, kt, half) do {                                              \
    int k0_ = ((kt) * 64) & (K - 1);                                              \
    _Pragma("unroll")                                                             \
    for (int c_ = 0; c_ < 2; ++c_) {                                              \
        int li_  = tid + c_ * 512;                                                \
        int row_ = li_ >> 3;                                                      \
        int sw_  = (li_ & 7) ^ (row_ & 7);                                        \
        gload16(A + (size_t)(mbase + (half) * 128 + row_) * K + k0_ + sw_ * 8,    \
                lds + (base) + (half) * 16384 + li_ * 16);                        \
    } } while (0)

#define STAGEB8(base, kt, half) do {                                              \
    int k0_ = ((kt) * 64) & (K - 1);                                              \
    _Pragma("unroll")                                                             \
    for (int c_ = 0; c_ < 2; ++c_) {                                              \
        int li_  = tid + c_ * 512;                                                \
        int row_ = li_ >> 3;                                                      \
        int sw_  = (li_ & 7) ^ (row_ & 7);                                        \
        gload16(Bt + (size_t)(nbase + (half) * 128 + row_) * K + k0_ + sw_ * 8,   \
                lds + (base) + (half) * 16384 + li_ * 16);                        \
    } } while (0)

#define LOADB8(base) do {                                                         \
    _Pragma("unroll")                                                             \
    for (int n_ = 0; n_ < 4; ++n_) {                                              \
        _Pragma("unroll")                                                         \
        for (int kk_ = 0; kk_ < 2; ++kk_) {                                       \
            int row_  = wn * 64 + n_ * 16 + q16;                                  \
            int byte_ = (row_ * 128 + kk_ * 64 + g * 16) ^ ((row_ & 7) << 4);     \
            bfr[kk_ * 4 + n_] = *reinterpret_cast<const bf16x8*>(lds + (base) + byte_); \
        } } } while (0)

#define LOADAQ8(base, quad) do {                                                  \
    _Pragma("unroll")                                                             \
    for (int mi_ = 0; mi_ < 2; ++mi_) {                                           \
        _Pragma("unroll")                                                         \
        for (int kk_ = 0; kk_ < 2; ++kk_) {                                       \
            int row_  = wm * 128 + ((quad) * 2 + mi_) * 16 + q16;                 \
            int byte_ = (row_ * 128 + kk_ * 64 + g * 16) ^ ((row_ & 7) << 4);     \
            af[mi_ * 2 + kk_] = *reinterpret_cast<const bf16x8*>(lds + (base) + byte_); \
        } } } while (0)

#define MFMAQ8(quad) do {                                                         \
    __builtin_amdgcn_s_setprio(1);                                                \
    _Pragma("unroll")                                                             \
    for (int mi_ = 0; mi_ < 2; ++mi_) {                                           \
        _Pragma("unroll")                                                         \
        for (int kk_ = 0; kk_ < 2; ++kk_) {                                       \
            _Pragma("unroll")                                                     \
            for (int n_ = 0; n_ < 4; ++n_)                                        \
                acc[(quad) * 2 + mi_][n_] = __builtin_amdgcn_mfma_f32_16x16x32_bf16( \
                    af[mi_ * 2 + kk_], bfr[kk_ * 4 + n_], acc[(quad) * 2 + mi_][n_], 0, 0, 0); \
        } }                                                                       \
    __builtin_amdgcn_s_setprio(0); } while (0)

#define BAR_LGKM do {                                                             \
    __builtin_amdgcn_s_barrier();                                                 \
    asm volatile("s_waitcnt lgkmcnt(0)" ::: "memory");                            \
    __builtin_amdgcn_sched_barrier(0); } while (0)

template<int MODE>
__global__ __launch_bounds__(512, 2) void gemm8_kernel(
    const bf16_t* __restrict__ A, const bf16_t* __restrict__ Bt,
    float* __restrict__ Cout,
    bf16_t* __restrict__ Qo, bf16_t* __restrict__ Ko, bf16_t* __restrict__ Vt,
    int M, int N, int K)
{
    __shared__ __align__(16) char lds[131072];
    const int tid  = threadIdx.x;
    const int lane = tid & 63;
    const int wid  = tid >> 6;
    const int wm   = wid >> 2, wn = wid & 3;   // 2M x 4N waves
    const int q16  = lane & 15, g = lane >> 4;
    const int mbase = blockIdx.y * 256;
    const int nbase = blockIdx.x * 256;
    const int NITER = K >> 7;                  // 2 K-tiles (BK=64) per iter

    f32x4  acc[8][4] = {};
    bf16x8 bfr[8], af[4];

    // ---- prologue: K0 -> buf0 (A+B), K1.B -> buf1.B ----
    STAGEB8(LB0, 0, 0); STAGEB8(LB0, 0, 1);
    STAGEA8(LA0, 0, 0); STAGEA8(LA0, 0, 1);
    STAGEB8(LB1, 1, 0); STAGEB8(LB1, 1, 1);
    asm volatile("s_waitcnt vmcnt(4)" ::: "memory");   // K0 A+B landed
    __builtin_amdgcn_s_barrier();
    __builtin_amdgcn_sched_barrier(0);

    #pragma unroll 1
    for (int i = 0; i < NITER; ++i) {
        const int kb = 2 * i + 1;
        const int kn = 2 * i + 2;
        // p0: consume buf0 quad0; stage K(2i+1).A -> buf1.A
        LOADB8(LB0); LOADAQ8(LA0, 0);
        STAGEA8(LA1, kb, 0); STAGEA8(LA1, kb, 1);
        BAR_LGKM; MFMAQ8(0);
        __builtin_amdgcn_s_barrier();
        // p1
        LOADAQ8(LA0, 1); STAGEB8(LB0, kn, 0);
        BAR_LGKM; MFMAQ8(1);
        __builtin_amdgcn_s_barrier();
        // p2
        LOADAQ8(LA0, 2); STAGEB8(LB0, kn, 1);
        BAR_LGKM; MFMAQ8(2);
        __builtin_amdgcn_s_barrier();
        // p3 (+vmcnt: buf1 = K(2i+1) complete before p4 reads)
        LOADAQ8(LA0, 3);
        BAR_LGKM; MFMAQ8(3);
        asm volatile("s_waitcnt vmcnt(4)" ::: "memory");
        __builtin_amdgcn_s_barrier();
        // p4: consume buf1 quad0; stage K(2i+2).A -> buf0.A
        LOADB8(LB1); LOADAQ8(LA1, 0);
        STAGEA8(LA0, kn, 0);
        BAR_LGKM; MFMAQ8(0);
        __builtin_amdgcn_s_barrier();
        // p5
        LOADAQ8(LA1, 1); STAGEA8(LA0, kn, 1);
        BAR_LGKM; MFMAQ8(1);
        __builtin_amdgcn_s_barrier();
        // p6
        LOADAQ8(LA1, 2); STAGEB8(LB1, kn + 1, 0);
        BAR_LGKM; MFMAQ8(2);
        __builtin_amdgcn_s_barrier();
        // p7 (+vmcnt: buf0 = K(2i+2) complete before next p0 reads)
        LOADAQ8(LA1, 3); STAGEB8(LB1, kn + 1, 1);
        BAR_LGKM; MFMAQ8(3);
        asm volatile("s_waitcnt vmcnt(4)" ::: "memory");
        __builtin_amdgcn_s_barrier();
    }
    asm volatile("s_waitcnt vmcnt(0)" ::: "memory");   // drain tail prefetches

    // ---- epilogue: C/D layout col = q16, row = g*4 + r ----
    #pragma unroll
    for (int mi = 0; mi < 8; ++mi) {
        #pragma unroll
        for (int n = 0; n < 4; ++n) {
            #pragma unroll
            for (int r = 0; r < 4; ++r) {
                int row = mbase + wm * 128 + mi * 16 + g * 4 + r;
                int col = nbase + wn * 64 + n * 16 + q16;
                float cval = acc[mi][n][r];
                if (MODE == 0) {
                    Cout[(size_t)row * N + col] = cval;
                } else {
                    int b = row >> 11, t = row & 2047;
                    int d = col & 63;
                    if (col < 1024) {
                        int h = col >> 6;
                        Qo[((size_t)(b * NH + h) * T_ + t) * HD + d] = (bf16_t)(cval * QSCALE);
                    } else if (col < 2048) {
                        int h = (col - 1024) >> 6;
                        Ko[((size_t)(b * NH + h) * T_ + t) * HD + d] = (bf16_t)cval;
                    } else {
                        int h = (col - 2048) >> 6;
                        Vt[((size_t)(b * NH + h) * HD + d) * T_ + t] = (bf16_t)cval;
                    }
                }
            }
        }
    }
}

// ---------------- flash attention (swapped-operand, in-register softmax) ----------------
__global__ __launch_bounds__(256) void attn_kernel(
    const bf16_t* __restrict__ Q, const bf16_t* __restrict__ K,
    const bf16_t* __restrict__ Vt, bf16_t* __restrict__ out)
{
    __shared__ __align__(16) char kvbuf[2][16384];   // [buf][ K 8KB | V 8KB ]
    __shared__ __align__(16) char plds[4][2048];     // per-wave 16q x 64kv bf16 P^T patch
    const int tid  = threadIdx.x;
    const int lane = tid & 63;
    const int wid  = tid >> 6;
    const int g    = lane >> 4;
    const int q16  = lane & 15;

    const int id  = blockIdx.x;          // 0..1023
    const int xcd = id & 7;
    const int k2  = id >> 3;
    const int bh  = xcd * 8 + (k2 >> 4);
    const int j   = k2 & 15;
    const int b   = bh >> 4, h = bh & 15;

    const bf16_t* Qh = Q  + (size_t)bh * T_ * HD;
    const bf16_t* Kh = K  + (size_t)bh * T_ * HD;
    const bf16_t* Vh = Vt + (size_t)bh * HD * T_;
    char* myp = plds[wid];
    const int pswz = (q16 & 7) << 4;

#define STAGE(buf, kv0) do {                                                     \
        _Pragma("unroll")                                                        \
        for (int c = 0; c < 2; ++c) {                                            \
            int li  = tid + c * 256;                                             \
            int row = li >> 3;                                                   \
            int sw  = (li & 7) ^ (row & 7);                                      \
            gload16(Kh + (size_t)((kv0) + row) * HD + sw * 8, (char*)(buf) + li * 16);          \
            gload16(Vh + (size_t)row * T_ + (kv0) + sw * 8, (char*)(buf) + 8192 + li * 16);     \
        } } while (0)

    #pragma unroll 1
    for (int part = 0; part < 2; ++part) {
        const int qtile = part ? j : (31 - j);
        const int nt    = qtile + 1;
        const int qbase = qtile * 64 + wid * 16;
        const int qg    = qbase + q16;

        bf16x8 qf[2];
        #pragma unroll
        for (int kk = 0; kk < 2; ++kk)
            qf[kk] = *reinterpret_cast<const bf16x8*>(
                Qh + (size_t)qg * HD + kk * 32 + g * 8);

        f32x4 accT[4] = {};
        float m = -1e30f, l = 0.f;

        STAGE(kvbuf[0], 0);
        int cur = 0;
        for (int it = 0; it < nt; ++it) {
            const int kv0 = it * 64;
            if (it + 1 < nt) {
                STAGE(kvbuf[cur ^ 1], (it + 1) * 64);
                asm volatile("s_waitcnt vmcnt(4)" ::: "memory");
            } else {
                asm volatile("s_waitcnt vmcnt(0)" ::: "memory");
            }
            __builtin_amdgcn_s_barrier();
            __builtin_amdgcn_sched_barrier(0);
            const char* Kl = kvbuf[cur];
            const char* Vl = kvbuf[cur] + 8192;

            f32x4 s4[4];
            __builtin_amdgcn_s_setprio(1);
            #pragma unroll
            for (int t = 0; t < 4; ++t) {
                f32x4 a = {};
                #pragma unroll
                for (int kk = 0; kk < 2; ++kk) {
                    int row  = t * 16 + q16;
                    int byte = (row * 128 + kk * 64 + g * 16) ^ ((row & 7) << 4);
                    bf16x8 kf = *reinterpret_cast<const bf16x8*>(Kl + byte);
                    a = __builtin_amdgcn_mfma_f32_16x16x32_bf16(kf, qf[kk], a, 0, 0, 0);
                }
                s4[t] = a;
            }
            __builtin_amdgcn_s_setprio(0);
            if (it == nt - 1) {
                #pragma unroll
                for (int t = 0; t < 4; ++t)
                    #pragma unroll
                    for (int r = 0; r < 4; ++r)
                        if (kv0 + t * 16 + g * 4 + r > qg) s4[t][r] = -1e30f;
            }
            float mt = fmaxf(fmaxf(s4[0][0], s4[0][1]), fmaxf(s4[0][2], s4[0][3]));
            #pragma unroll
            for (int t = 1; t < 4; ++t)
                mt = fmaxf(mt, fmaxf(fmaxf(s4[t][0], s4[t][1]), fmaxf(s4[t][2], s4[t][3])));
            mt = fmaxf(mt, __shfl_xor(mt, 16, 64));
            mt = fmaxf(mt, __shfl_xor(mt, 32, 64));
            if (!__all(mt <= m + 8.f)) {
                float mn = fmaxf(m, mt);
                float alpha = exp2f(m - mn);
                m = mn;
                l *= alpha;
                #pragma unroll
                for (int nf = 0; nf < 4; ++nf)
                    #pragma unroll
                    for (int r = 0; r < 4; ++r)
                        accT[nf][r] *= alpha;
            }
            float rs = 0.f;
            #pragma unroll
            for (int t = 0; t < 4; ++t) {
                float p0 = exp2f(s4[t][0] - m);
                float p1 = exp2f(s4[t][1] - m);
                float p2 = exp2f(s4[t][2] - m);
                float p3 = exp2f(s4[t][3] - m);
                rs += (p0 + p1) + (p2 + p3);
                bf16x4 pw = { (bf16_t)p0, (bf16_t)p1, (bf16_t)p2, (bf16_t)p3 };
                int byte = (q16 * 128 + t * 32 + g * 8) ^ pswz;
                *reinterpret_cast<bf16x4*>(myp + byte) = pw;
            }
            rs += __shfl_xor(rs, 16, 64);
            rs += __shfl_xor(rs, 32, 64);
            l += rs;
            asm volatile("s_waitcnt lgkmcnt(0)" ::: "memory");
            __builtin_amdgcn_sched_barrier(0);
            bf16x8 pf[2];
            #pragma unroll
            for (int kk2 = 0; kk2 < 2; ++kk2) {
                int byte = (q16 * 128 + kk2 * 64 + g * 16) ^ pswz;
                pf[kk2] = *reinterpret_cast<const bf16x8*>(myp + byte);
            }
            __builtin_amdgcn_s_setprio(1);
            #pragma unroll
            for (int nf = 0; nf < 4; ++nf) {
                #pragma unroll
                for (int kk2 = 0; kk2 < 2; ++kk2) {
                    int row  = nf * 16 + q16;
                    int byte = (row * 128 + kk2 * 64 + g * 16) ^ ((row & 7) << 4);
                    bf16x8 vf = *reinterpret_cast<const bf16x8*>(Vl + byte);
                    accT[nf] = __builtin_amdgcn_mfma_f32_16x16x32_bf16(vf, pf[kk2], accT[nf], 0, 0, 0);
                }
            }
            __builtin_amdgcn_s_setprio(0);
            __syncthreads();
            cur ^= 1;
        }
        float inv = 1.f / l;
        #pragma unroll
        for (int nf = 0; nf < 4; ++nf) {
            bf16x4 ov = { (bf16_t)(accT[nf][0] * inv), (bf16_t)(accT[nf][1] * inv),
                          (bf16_t)(accT[nf][2] * inv), (bf16_t)(accT[nf][3] * inv) };
            *reinterpret_cast<bf16x4*>(
                out + (size_t)(b * T_ + qg) * C_ + h * HD + nf * 16 + g * 4) = ov;
        }
    }
#undef STAGE
}

// ---------------- launch ----------------
extern "C" void kernel_launch(void* const* d_in, const int* in_sizes, int n_in,
                              void* d_out, int out_size, void* d_ws, size_t ws_size,
                              hipStream_t stream) {
    const float* x      = (const float*)d_in[0];
    const float* w_qkv  = (const float*)d_in[1];
    const float* w_proj = (const float*)d_in[2];
    float* out = (float*)d_out;

    char* ws = (char*)d_ws;
    bf16_t* xb     = (bf16_t*)(ws);                  // 16,777,216 B
    bf16_t* wqkvT  = (bf16_t*)(ws + 16777216);       //  6,291,456 B
    bf16_t* wprojT = (bf16_t*)(ws + 23068672);       //  2,097,152 B
    bf16_t* Qb     = (bf16_t*)(ws + 25165824);       // 16,777,216 B
    bf16_t* Kb     = (bf16_t*)(ws + 41943040);       // 16,777,216 B
    bf16_t* Vtb    = (bf16_t*)(ws + 58720256);       // 16,777,216 B
    bf16_t* attnb  = (bf16_t*)(ws + 75497472);       // 16,777,216 B

    conv_x_kernel<<<2048, 256, 0, stream>>>(x, xb, (B_ * T_ * C_) / 4);
    transpose_w_kernel<<<dim3(3 * C_ / 32, C_ / 32), dim3(32, 8), 0, stream>>>(w_qkv, wqkvT, C_, 3 * C_);
    transpose_w_kernel<<<dim3(C_ / 32, C_ / 32), dim3(32, 8), 0, stream>>>(w_proj, wprojT, C_, C_);

    gemm8_kernel<1><<<dim3(3 * C_ / 256, M_TOT / 256), 512, 0, stream>>>(
        xb, wqkvT, nullptr, Qb, Kb, Vtb, M_TOT, 3 * C_, C_);

    attn_kernel<<<1024, 256, 0, stream>>>(Qb, Kb, Vtb, attnb);

    gemm8_kernel<0><<<dim3(C_ / 256, M_TOT / 256), 512, 0, stream>>>(
        attnb, wprojT, out, nullptr, nullptr, nullptr, M_TOT, C_, C_);
}